// Round 1
// baseline (37000.879 us; speedup 1.0000x reference)
//
#include <hip/hip_runtime.h>
#include <math.h>

// ---- problem constants ----
#define Bsz 16
#define KIMG 2
#define NPP 14
#define PSZ 16
#define E 768
#define NH 12
#define HS 64
#define NL 12
#define NGT 32
#define NGI 196
#define NI 392
#define T 621           // NGT + NGI + NI + 1
#define TOK (Bsz * T)   // 9936
#define FF 3072
#define G1 228          // NGT+NGI
#define G2 424          // G1+196
#define G3 620          // G1+392
#define LN_EPS 1e-5f

// ================= POS embedding (f64 math, matches numpy) =================
__global__ __launch_bounds__(256) void pos_fill(float* __restrict__ pos) {
    int idx = blockIdx.x * 256 + threadIdx.x;
    if (idx >= T * E) return;
    int e = idx % E;
    int t = idx / E;
    int jj = (e & 1) ? (e - 1) : e;
    double expo = (double)jj / (double)E;
    double ang = (double)t / pow(10000.0, expo);
    pos[idx] = (float)((e & 1) ? cos(ang) : sin(ang));
}

// ============ text + action token embedding ============
__global__ __launch_bounds__(256) void embed_txt_act(
    const int* __restrict__ goals_txt, const float* __restrict__ text_emb,
    const float* __restrict__ action_emb, const float* __restrict__ pos,
    float* __restrict__ x)
{
    int idx = blockIdx.x * 256 + threadIdx.x;  // over Bsz*33*E
    if (idx >= Bsz * 33 * E) return;
    int e = idx % E;
    int r = idx / E;
    int b = r / 33;
    int tt = r % 33;
    int t; float val;
    if (tt < NGT) {
        t = tt;
        int tok = goals_txt[b * NGT + tt];
        val = text_emb[(size_t)tok * E + e];
    } else {
        t = G3;  // 620
        val = action_emb[e];
    }
    x[((size_t)(b * T + t)) * E + e] = val + pos[(size_t)t * E + e];
}

// ============ patch extraction: (B,588,768) with gimg first ============
__global__ __launch_bounds__(256) void patch_ext(
    const float* __restrict__ images, const float* __restrict__ goal_imgs,
    float* __restrict__ patches)
{
    size_t idx = (size_t)blockIdx.x * 256 + threadIdx.x;  // over 9408*768
    if (idx >= (size_t)Bsz * 588 * E) return;
    int j = (int)(idx % E);
    int r = (int)(idx / E);
    int b = r / 588;
    int rr = r % 588;
    int pr = j / 48;
    int rem = j % 48;
    int pc = rem / 3;
    int c = rem % 3;
    float v;
    if (rr < NGI) {  // goal image patches
        int pi = rr;
        int nr = pi / NPP, nc = pi % NPP;
        size_t src = ((size_t)b * 224 + (nr * PSZ + pr)) * 224 * 3
                   + (size_t)(nc * PSZ + pc) * 3 + c;
        v = goal_imgs[src];
    } else {         // observation image patches
        int q = rr - NGI;
        int kk = q / NGI;
        int pi = q % NGI;
        int nr = pi / NPP, nc = pi % NPP;
        size_t src = (((size_t)(b * KIMG + kk)) * 224 + (nr * PSZ + pr)) * 224 * 3
                   + (size_t)(nc * PSZ + pc) * 3 + c;
        v = images[src];
    }
    patches[idx] = v;
}

// ============ scatter patch embeddings into x with bias+pos ============
__global__ __launch_bounds__(256) void patch_scatter(
    const float* __restrict__ emb, const float* __restrict__ patch_b,
    const float* __restrict__ pos, float* __restrict__ x)
{
    size_t idx = (size_t)blockIdx.x * 256 + threadIdx.x;  // over 9408*768
    if (idx >= (size_t)Bsz * 588 * E) return;
    int e = (int)(idx % E);
    int r = (int)(idx / E);
    int b = r / 588;
    int rr = r % 588;
    int t = NGT + rr;  // 32..619
    x[((size_t)(b * T + t)) * E + e] = emb[idx] + patch_b[e] + pos[(size_t)t * E + e];
}

// ================= generic f32 GEMM =================
// C[M,N] = A[M,K] @ B[K,N] (+epilogue). mode: 0=plain, 1=+bias, 2=relu(+bias), 3=C+= acc+bias (residual)
// bqkv: B element (k,c) read from W[(c>>6)*K*64 + k*64 + (c&63)]  (H,E,HS layout)
__global__ __launch_bounds__(256) void gemm_f32(
    const float* __restrict__ A, const float* __restrict__ Bm,
    float* __restrict__ C, const float* __restrict__ bias,
    int M, int N, int Kd, int mode, int bqkv)
{
    __shared__ float As[16][64];
    __shared__ float Bs[16][64];
    int tid = threadIdx.x;
    int row0 = blockIdx.y * 64;
    int col0 = blockIdx.x * 64;
    int ty = tid >> 4, tx = tid & 15;
    float acc[4][4] = {};

    for (int k0 = 0; k0 < Kd; k0 += 16) {
        // A tile 64x16: each thread one float4
        {
            int mm = tid >> 2;
            int kk0 = (tid & 3) * 4;
            int gr = row0 + mm;
            float4 av = make_float4(0.f, 0.f, 0.f, 0.f);
            if (gr < M) av = *(const float4*)&A[(size_t)gr * Kd + k0 + kk0];
            As[kk0 + 0][mm] = av.x;
            As[kk0 + 1][mm] = av.y;
            As[kk0 + 2][mm] = av.z;
            As[kk0 + 3][mm] = av.w;
        }
        // B tile 16x64: each thread one float4
        {
            int kk2 = tid >> 4;
            int nn0 = (tid & 15) * 4;
            int gc = col0 + nn0;
            float4 bv;
            if (bqkv) {
                const float* bp = Bm + (size_t)(gc >> 6) * Kd * HS
                                    + (size_t)(k0 + kk2) * HS + (gc & 63);
                bv = *(const float4*)bp;
            } else {
                bv = *(const float4*)&Bm[(size_t)(k0 + kk2) * N + gc];
            }
            *(float4*)&Bs[kk2][nn0] = bv;
        }
        __syncthreads();
        #pragma unroll
        for (int kk2 = 0; kk2 < 16; ++kk2) {
            float4 a4 = *(const float4*)&As[kk2][ty * 4];
            float4 b4 = *(const float4*)&Bs[kk2][tx * 4];
            float a[4] = {a4.x, a4.y, a4.z, a4.w};
            float bb[4] = {b4.x, b4.y, b4.z, b4.w};
            #pragma unroll
            for (int i = 0; i < 4; ++i)
                #pragma unroll
                for (int j = 0; j < 4; ++j)
                    acc[i][j] += a[i] * bb[j];
        }
        __syncthreads();
    }

    int gc = col0 + tx * 4;
    float4 bi = make_float4(0.f, 0.f, 0.f, 0.f);
    if (mode >= 1) bi = *(const float4*)&bias[gc];
    #pragma unroll
    for (int i = 0; i < 4; ++i) {
        int gr = row0 + ty * 4 + i;
        if (gr >= M) continue;
        float4 r;
        r.x = acc[i][0] + bi.x;
        r.y = acc[i][1] + bi.y;
        r.z = acc[i][2] + bi.z;
        r.w = acc[i][3] + bi.w;
        if (mode == 2) {
            r.x = fmaxf(r.x, 0.f); r.y = fmaxf(r.y, 0.f);
            r.z = fmaxf(r.z, 0.f); r.w = fmaxf(r.w, 0.f);
        }
        float* cp = &C[(size_t)gr * N + gc];
        if (mode == 3) {
            float4 old = *(const float4*)cp;
            r.x += old.x; r.y += old.y; r.z += old.z; r.w += old.w;
        }
        *(float4*)cp = r;
    }
}

// ================= LayerNorm =================
__global__ __launch_bounds__(256) void ln_kernel(
    const float* __restrict__ x, float* __restrict__ h,
    const float* __restrict__ sg, const float* __restrict__ bg)
{
    int row = blockIdx.x;
    int tid = threadIdx.x;
    const float* xr = x + (size_t)row * E;
    float v0 = xr[tid], v1 = xr[tid + 256], v2 = xr[tid + 512];
    float sum = v0 + v1 + v2;
    float sq = v0 * v0 + v1 * v1 + v2 * v2;
    #pragma unroll
    for (int off = 1; off < 64; off <<= 1) {
        sum += __shfl_xor(sum, off);
        sq += __shfl_xor(sq, off);
    }
    __shared__ float rs[4], rq[4];
    if ((tid & 63) == 0) { rs[tid >> 6] = sum; rq[tid >> 6] = sq; }
    __syncthreads();
    float ts = rs[0] + rs[1] + rs[2] + rs[3];
    float tq = rq[0] + rq[1] + rq[2] + rq[3];
    float mean = ts * (1.0f / E);
    float var = tq * (1.0f / E) - mean * mean;
    float inv = 1.0f / sqrtf(var + LN_EPS);
    float* hr = h + (size_t)row * E;
    hr[tid]       = (v0 - mean) * inv * sg[tid]       + bg[tid];
    hr[tid + 256] = (v1 - mean) * inv * sg[tid + 256] + bg[tid + 256];
    hr[tid + 512] = (v2 - mean) * inv * sg[tid + 512] + bg[tid + 512];
}

// ================= attention: one wave per (b,h,t) =================
__device__ __forceinline__ bool keep_mask(int t, int s) {
    if (s == t) return true;
    if (s < NGT) return !(t >= NGT && t < G1);
    if (s >= G1 && s < G2) return t >= G1;
    if (s >= G2 && s < G3) return t >= G2;
    return false;
}

__global__ __launch_bounds__(256) void attn_kernel(
    const float* __restrict__ q, const float* __restrict__ k,
    const float* __restrict__ v, float* __restrict__ o)
{
    __shared__ float sm[4][64 + 640];
    int wslot = threadIdx.x >> 6;
    int lane = threadIdx.x & 63;
    int wid = blockIdx.x * 4 + wslot;   // exact grid: B*H*T waves
    int t = wid % T;
    int bh = wid / T;
    int hh = bh % NH;
    int b = bh / NH;
    float* qs = sm[wslot];
    float* sc = sm[wslot] + 64;
    size_t base = ((size_t)b * T) * E + (size_t)hh * HS;

    qs[lane] = q[base + (size_t)t * E + lane];
    __syncthreads();

    const float scale = 0.03608439182435161f;  // 768^-0.5
    float val[10];
    #pragma unroll
    for (int c = 0; c < 10; ++c) {
        int s = c * 64 + lane;
        float acc = -INFINITY;
        if (s < T && keep_mask(t, s)) {
            const float* krow = k + base + (size_t)s * E;
            float a0 = 0.f;
            #pragma unroll
            for (int d4 = 0; d4 < 16; ++d4) {
                float4 qv = *(const float4*)&qs[d4 * 4];
                float4 kv = *(const float4*)&krow[d4 * 4];
                a0 += qv.x * kv.x + qv.y * kv.y + qv.z * kv.z + qv.w * kv.w;
            }
            acc = a0 * scale;
        }
        val[c] = acc;
    }
    float mx = -INFINITY;
    #pragma unroll
    for (int c = 0; c < 10; ++c) mx = fmaxf(mx, val[c]);
    #pragma unroll
    for (int off = 1; off < 64; off <<= 1) mx = fmaxf(mx, __shfl_xor(mx, off));
    float ssum = 0.f;
    float p[10];
    #pragma unroll
    for (int c = 0; c < 10; ++c) { p[c] = __expf(val[c] - mx); ssum += p[c]; }
    #pragma unroll
    for (int off = 1; off < 64; off <<= 1) ssum += __shfl_xor(ssum, off);
    float inv = 1.0f / ssum;
    #pragma unroll
    for (int c = 0; c < 10; ++c) sc[c * 64 + lane] = p[c] * inv;
    __syncthreads();

    float oacc = 0.f;
    if (t < NGT) {
        for (int s = 0; s < NGT; ++s)
            oacc += sc[s] * v[base + (size_t)s * E + lane];
    } else if (t < G1) {
        oacc = sc[t] * v[base + (size_t)t * E + lane];  // attends only to itself
    } else {
        for (int s = 0; s < NGT; ++s)
            oacc += sc[s] * v[base + (size_t)s * E + lane];
        for (int s = G1; s < G2; ++s)
            oacc += sc[s] * v[base + (size_t)s * E + lane];
        if (t >= G2)
            for (int s = G2; s < G3; ++s)
                oacc += sc[s] * v[base + (size_t)s * E + lane];
        if (t == G3)
            oacc += sc[G3] * v[base + (size_t)G3 * E + lane];
    }
    o[base + (size_t)t * E + lane] = oacc;
}

// ================= output head =================
__global__ __launch_bounds__(256) void head_kernel(
    const float* __restrict__ x, const float* __restrict__ hw1,
    const float* __restrict__ hb1, const float* __restrict__ hw2,
    const float* __restrict__ hb2, float* __restrict__ out)
{
    int b = blockIdx.x;
    int tid = threadIdx.x;
    __shared__ float z[E];
    __shared__ float a1[E];
    const float* xr = x + ((size_t)(b * T + G3)) * E;
    for (int i = tid; i < E; i += 256) z[i] = xr[i];
    __syncthreads();
    for (int col = tid; col < E; col += 256) {
        float acc = hb1[col];
        for (int e = 0; e < E; ++e) acc += z[e] * hw1[(size_t)e * E + col];
        a1[col] = fmaxf(acc, 0.f);
    }
    __syncthreads();
    for (int col = tid; col < 64; col += 256) {
        float acc = hb2[col];
        for (int e = 0; e < E; ++e) acc += a1[e] * hw2[(size_t)e * 64 + col];
        out[b * 64 + col] = acc;
    }
}

// ================= launch =================
extern "C" void kernel_launch(void* const* d_in, const int* in_sizes, int n_in,
                              void* d_out, int out_size, void* d_ws, size_t ws_size,
                              hipStream_t stream) {
    const float* images     = (const float*)d_in[0];
    const int*   goals_txt  = (const int*)d_in[1];
    const float* goal_imgs  = (const float*)d_in[2];
    const float* patch_w    = (const float*)d_in[3];
    const float* patch_b    = (const float*)d_in[4];
    const float* text_emb   = (const float*)d_in[5];
    const float* action_emb = (const float*)d_in[6];
    const float* wq         = (const float*)d_in[7];
    const float* wk         = (const float*)d_in[8];
    const float* wv         = (const float*)d_in[9];
    const float* proj_w     = (const float*)d_in[10];
    const float* proj_b     = (const float*)d_in[11];
    const float* ln1_s      = (const float*)d_in[12];
    const float* ln1_b      = (const float*)d_in[13];
    const float* ln2_s      = (const float*)d_in[14];
    const float* ln2_b      = (const float*)d_in[15];
    const float* ff_w1      = (const float*)d_in[16];
    const float* ff_b1      = (const float*)d_in[17];
    const float* ff_w2      = (const float*)d_in[18];
    const float* ff_b2      = (const float*)d_in[19];
    const float* hw1        = (const float*)d_in[20];
    const float* hb1        = (const float*)d_in[21];
    const float* hw2        = (const float*)d_in[22];
    const float* hb2        = (const float*)d_in[23];
    float* out = (float*)d_out;

    float* ws = (float*)d_ws;
    const size_t SZ = (size_t)TOK * E;   // 7,630,848 floats
    float* x   = ws;
    float* h   = ws + SZ;
    float* qb  = ws + 2 * SZ;
    float* kb  = ws + 3 * SZ;
    float* vb  = ws + 4 * SZ;
    float* ob  = ws + 5 * SZ;
    float* ffh = ws + 6 * SZ;            // TOK*FF floats
    float* patches = ffh;                // alias: patches dead before FF runs
    float* pos = ws + 6 * SZ + (size_t)TOK * FF;

    // POS table
    pos_fill<<<(T * E + 255) / 256, 256, 0, stream>>>(pos);
    // text + action tokens
    embed_txt_act<<<(Bsz * 33 * E + 255) / 256, 256, 0, stream>>>(
        goals_txt, text_emb, action_emb, pos, x);
    // patches -> embed -> scatter
    const size_t NPATCH_EL = (size_t)Bsz * 588 * E;  // 7,225,344
    patch_ext<<<(int)((NPATCH_EL + 255) / 256), 256, 0, stream>>>(images, goal_imgs, patches);
    gemm_f32<<<dim3(E / 64, (Bsz * 588 + 63) / 64), 256, 0, stream>>>(
        patches, patch_w, h, nullptr, Bsz * 588, E, E, 0, 0);
    patch_scatter<<<(int)((NPATCH_EL + 255) / 256), 256, 0, stream>>>(h, patch_b, pos, x);

    const int gy = (TOK + 63) / 64;  // 156
    for (int l = 0; l < NL; ++l) {
        ln_kernel<<<TOK, 256, 0, stream>>>(x, h, ln1_s + l * E, ln1_b + l * E);
        gemm_f32<<<dim3(E / 64, gy), 256, 0, stream>>>(
            h, wq + (size_t)l * NH * E * HS, qb, nullptr, TOK, E, E, 0, 1);
        gemm_f32<<<dim3(E / 64, gy), 256, 0, stream>>>(
            h, wk + (size_t)l * NH * E * HS, kb, nullptr, TOK, E, E, 0, 1);
        gemm_f32<<<dim3(E / 64, gy), 256, 0, stream>>>(
            h, wv + (size_t)l * NH * E * HS, vb, nullptr, TOK, E, E, 0, 1);
        attn_kernel<<<(Bsz * NH * T) / 4, 256, 0, stream>>>(qb, kb, vb, ob);
        gemm_f32<<<dim3(E / 64, gy), 256, 0, stream>>>(
            ob, proj_w + (size_t)l * E * E, x, proj_b + (size_t)l * E, TOK, E, E, 3, 0);
        ln_kernel<<<TOK, 256, 0, stream>>>(x, h, ln2_s + l * E, ln2_b + l * E);
        gemm_f32<<<dim3(FF / 64, gy), 256, 0, stream>>>(
            h, ff_w1 + (size_t)l * E * FF, ffh, ff_b1 + (size_t)l * FF, TOK, FF, E, 2, 0);
        gemm_f32<<<dim3(E / 64, gy), 256, 0, stream>>>(
            ffh, ff_w2 + (size_t)l * FF * E, x, ff_b2 + (size_t)l * E, TOK, E, FF, 3, 0);
    }
    head_kernel<<<Bsz, 256, 0, stream>>>(x, hw1, hb1, hw2, hb2, out);
}

// Round 2
// 10052.029 us; speedup vs baseline: 3.6809x; 3.6809x over previous
//
#include <hip/hip_runtime.h>
#include <math.h>

// ---- problem constants ----
#define Bsz 16
#define KIMG 2
#define NPP 14
#define PSZ 16
#define E 768
#define NH 12
#define HS 64
#define NL 12
#define NGT 32
#define NGI 196
#define T 621           // NGT + NGI + NI + 1
#define TOK (Bsz * T)   // 9936
#define MP 9984         // TOK padded to 78*128
#define MP2 9472        // 9408 padded to 74*128
#define FF 3072
#define G1 228
#define G2 424
#define G3 620
#define LN_EPS 1e-5f

typedef __attribute__((ext_vector_type(8))) short bf16x8;
typedef __attribute__((ext_vector_type(4))) float f32x4;

__device__ __forceinline__ unsigned short f2bf(float f) {
    unsigned u = __float_as_uint(f);
    u += 0x7fffu + ((u >> 16) & 1u);   // RNE
    return (unsigned short)(u >> 16);
}
__device__ __forceinline__ float bfl(unsigned u) { return __uint_as_float(u << 16); }
__device__ __forceinline__ float bfh(unsigned u) { return __uint_as_float(u & 0xffff0000u); }

// ================= POS embedding (f64 math, matches numpy) =================
__global__ __launch_bounds__(256) void pos_fill(float* __restrict__ pos) {
    int idx = blockIdx.x * 256 + threadIdx.x;
    if (idx >= T * E) return;
    int e = idx % E;
    int t = idx / E;
    int jj = (e & 1) ? (e - 1) : e;
    double expo = (double)jj / (double)E;
    double ang = (double)t / pow(10000.0, expo);
    pos[idx] = (float)((e & 1) ? cos(ang) : sin(ang));
}

// ============ transpose+cast f32[R][C] -> bf16[C][R], batched ============
__global__ __launch_bounds__(256) void transpose_cast(
    const float* __restrict__ in, unsigned short* __restrict__ out,
    int R, int C, long inb, int per_g, long gs, long is)
{
    __shared__ float tl[32][33];
    int b = blockIdx.z;
    const float* ib = in + (size_t)b * inb;
    unsigned short* ob = out + (size_t)(b / per_g) * gs + (size_t)(b % per_g) * is;
    int tx = threadIdx.x, ty = threadIdx.y;
    int bx = blockIdx.x, by = blockIdx.y;
    #pragma unroll
    for (int i = 0; i < 4; ++i) {
        int r = by * 32 + ty + i * 8;
        int c = bx * 32 + tx;
        tl[ty + i * 8][tx] = ib[(size_t)r * C + c];
    }
    __syncthreads();
    #pragma unroll
    for (int i = 0; i < 4; ++i) {
        int orow = bx * 32 + ty + i * 8;
        int ocol = by * 32 + tx;
        ob[(size_t)orow * R + ocol] = f2bf(tl[tx][ty + i * 8]);
    }
}

// ============ text + action token embedding ============
__global__ __launch_bounds__(256) void embed_txt_act(
    const int* __restrict__ goals_txt, const float* __restrict__ text_emb,
    const float* __restrict__ action_emb, const float* __restrict__ pos,
    float* __restrict__ x)
{
    int idx = blockIdx.x * 256 + threadIdx.x;
    if (idx >= Bsz * 33 * E) return;
    int e = idx % E;
    int r = idx / E;
    int b = r / 33;
    int tt = r % 33;
    int t; float val;
    if (tt < NGT) {
        t = tt;
        int tok = goals_txt[b * NGT + tt];
        val = text_emb[(size_t)tok * E + e];
    } else {
        t = G3;
        val = action_emb[e];
    }
    x[((size_t)(b * T + t)) * E + e] = val + pos[(size_t)t * E + e];
}

// ============ patch extraction -> bf16 (B,588,768), gimg first ============
__global__ __launch_bounds__(256) void patch_ext(
    const float* __restrict__ images, const float* __restrict__ goal_imgs,
    unsigned short* __restrict__ patches)
{
    size_t idx = (size_t)blockIdx.x * 256 + threadIdx.x;
    if (idx >= (size_t)Bsz * 588 * E) return;
    int j = (int)(idx % E);
    int r = (int)(idx / E);
    int b = r / 588;
    int rr = r % 588;
    int pr = j / 48;
    int rem = j % 48;
    int pc = rem / 3;
    int c = rem % 3;
    float v;
    if (rr < NGI) {
        int pi = rr;
        int nr = pi / NPP, nc = pi % NPP;
        size_t src = ((size_t)b * 224 + (nr * PSZ + pr)) * 224 * 3
                   + (size_t)(nc * PSZ + pc) * 3 + c;
        v = goal_imgs[src];
    } else {
        int q = rr - NGI;
        int kk = q / NGI;
        int pi = q % NGI;
        int nr = pi / NPP, nc = pi % NPP;
        size_t src = (((size_t)(b * KIMG + kk)) * 224 + (nr * PSZ + pr)) * 224 * 3
                   + (size_t)(nc * PSZ + pc) * 3 + c;
        v = images[src];
    }
    patches[idx] = f2bf(v);
}

// ============ scatter patch embeddings into x with bias+pos ============
__global__ __launch_bounds__(256) void patch_scatter(
    const float* __restrict__ emb, const float* __restrict__ patch_b,
    const float* __restrict__ pos, float* __restrict__ x)
{
    size_t idx = (size_t)blockIdx.x * 256 + threadIdx.x;
    if (idx >= (size_t)Bsz * 588 * E) return;
    int e = (int)(idx % E);
    int r = (int)(idx / E);
    int b = r / 588;
    int rr = r % 588;
    int t = NGT + rr;
    x[((size_t)(b * T + t)) * E + e] = emb[idx] + patch_b[e] + pos[(size_t)t * E + e];
}

// ================= bf16 MFMA GEMM =================
// A bf16 [M][K] row-major, Bt bf16 [N][K] row-major (B transposed), tile 128x128, BK=32.
// mode: 0 = f32 out, 1 = bf16 out, 2 = bf16 out relu(acc+bias), 3 = f32 out += acc+bias
__global__ __launch_bounds__(256) void gemm_bf16(
    const unsigned short* __restrict__ A, const unsigned short* __restrict__ Bt,
    void* __restrict__ C, const float* __restrict__ bias,
    int N, int Kd, int mode)
{
    __shared__ unsigned short As[128 * 40];
    __shared__ unsigned short Bs[128 * 40];
    int tid = threadIdx.x;
    int row0 = blockIdx.y * 128, col0 = blockIdx.x * 128;
    int wave = tid >> 6, lane = tid & 63;
    f32x4 acc[2][8];
    #pragma unroll
    for (int i = 0; i < 2; ++i)
        #pragma unroll
        for (int j = 0; j < 8; ++j) {
            f32x4 z = {0.f, 0.f, 0.f, 0.f};
            acc[i][j] = z;
        }
    int sr = tid >> 2, sc = (tid & 3) * 8;
    const unsigned short* Ag = A + (size_t)(row0 + sr) * Kd + sc;
    const unsigned short* Bg = Bt + (size_t)(col0 + sr) * Kd + sc;
    for (int k0 = 0; k0 < Kd; k0 += 32) {
        uint4 a0 = *(const uint4*)(Ag + k0);
        uint4 a1 = *(const uint4*)(Ag + (size_t)64 * Kd + k0);
        uint4 b0 = *(const uint4*)(Bg + k0);
        uint4 b1 = *(const uint4*)(Bg + (size_t)64 * Kd + k0);
        __syncthreads();
        *(uint4*)&As[sr * 40 + sc] = a0;
        *(uint4*)&As[(sr + 64) * 40 + sc] = a1;
        *(uint4*)&Bs[sr * 40 + sc] = b0;
        *(uint4*)&Bs[(sr + 64) * 40 + sc] = b1;
        __syncthreads();
        bf16x8 af[2], bfr[8];
        int mrow = wave * 32;
        af[0] = *(bf16x8*)&As[(mrow + (lane & 15)) * 40 + (lane >> 4) * 8];
        af[1] = *(bf16x8*)&As[(mrow + 16 + (lane & 15)) * 40 + (lane >> 4) * 8];
        #pragma unroll
        for (int nt = 0; nt < 8; ++nt)
            bfr[nt] = *(bf16x8*)&Bs[(nt * 16 + (lane & 15)) * 40 + (lane >> 4) * 8];
        #pragma unroll
        for (int mt = 0; mt < 2; ++mt)
            #pragma unroll
            for (int nt = 0; nt < 8; ++nt)
                acc[mt][nt] = __builtin_amdgcn_mfma_f32_16x16x32_bf16(
                    af[mt], bfr[nt], acc[mt][nt], 0, 0, 0);
    }
    int q = lane >> 4, cl = lane & 15;
    #pragma unroll
    for (int mt = 0; mt < 2; ++mt) {
        #pragma unroll
        for (int nt = 0; nt < 8; ++nt) {
            int gcol = col0 + nt * 16 + cl;
            int grow0 = row0 + wave * 32 + mt * 16 + q * 4;
            float bv = (mode >= 2 && bias) ? bias[gcol] : 0.f;
            #pragma unroll
            for (int r = 0; r < 4; ++r) {
                float v = acc[mt][nt][r] + bv;
                size_t off = (size_t)(grow0 + r) * N + gcol;
                if (mode == 0)      ((float*)C)[off] = v;
                else if (mode == 1) ((unsigned short*)C)[off] = f2bf(v);
                else if (mode == 2) ((unsigned short*)C)[off] = f2bf(fmaxf(v, 0.f));
                else                ((float*)C)[off] += v;
            }
        }
    }
}

// ================= LayerNorm: f32 in, bf16 out =================
__global__ __launch_bounds__(256) void ln_kernel(
    const float* __restrict__ x, unsigned short* __restrict__ h,
    const float* __restrict__ sg, const float* __restrict__ bg)
{
    int row = blockIdx.x;
    int tid = threadIdx.x;
    const float* xr = x + (size_t)row * E;
    float v0 = xr[tid], v1 = xr[tid + 256], v2 = xr[tid + 512];
    float sum = v0 + v1 + v2;
    float sq = v0 * v0 + v1 * v1 + v2 * v2;
    #pragma unroll
    for (int off = 1; off < 64; off <<= 1) {
        sum += __shfl_xor(sum, off);
        sq += __shfl_xor(sq, off);
    }
    __shared__ float rs[4], rq[4];
    if ((tid & 63) == 0) { rs[tid >> 6] = sum; rq[tid >> 6] = sq; }
    __syncthreads();
    float ts = rs[0] + rs[1] + rs[2] + rs[3];
    float tq = rq[0] + rq[1] + rq[2] + rq[3];
    float mean = ts * (1.0f / E);
    float var = tq * (1.0f / E) - mean * mean;
    float inv = 1.0f / sqrtf(var + LN_EPS);
    unsigned short* hr = h + (size_t)row * E;
    hr[tid]       = f2bf((v0 - mean) * inv * sg[tid]       + bg[tid]);
    hr[tid + 256] = f2bf((v1 - mean) * inv * sg[tid + 256] + bg[tid + 256]);
    hr[tid + 512] = f2bf((v2 - mean) * inv * sg[tid + 512] + bg[tid + 512]);
}

// ================= attention (flash-style, bf16 qkv fused [t][2304]) =================
__device__ __forceinline__ bool keep2(int t, int s) {
    if (s < NGT) return true;       // active t's (t<32 or t>=228) always see text
    if (s < G1) return false;
    if (s < G2) return true;        // t >= 228 guaranteed when these chunks visited
    if (s < G3) return t >= G2;
    return t == G3;                 // s == 620
}

__global__ __launch_bounds__(256) void attn2(
    const unsigned short* __restrict__ qkv, unsigned short* __restrict__ ob)
{
    __shared__ float Qs[16][64];
    __shared__ float Ks[32][66];
    __shared__ float Vs[32][66];
    __shared__ float Ps[4][32];
    int tile = blockIdx.x;
    int bh = blockIdx.y;
    int h = bh % NH, b = bh / NH;
    int t0 = (tile < 2) ? tile * 16 : G1 + (tile - 2) * 16;
    int tid = threadIdx.x;
    int wave = tid >> 6, lane = tid & 63;
    size_t rowb = (size_t)b * T;

    {   // stage Q (16x64)
        int r = tid >> 4, c = (tid & 15) * 4;
        const ushort4 u = *(const ushort4*)(qkv + (rowb + t0 + r) * 2304 + h * 64 + c);
        Qs[r][c + 0] = bfl(u.x); Qs[r][c + 1] = bfl(u.y);
        Qs[r][c + 2] = bfl(u.z); Qs[r][c + 3] = bfl(u.w);
    }

    float m[4], l[4], o[4];
    #pragma unroll
    for (int j = 0; j < 4; ++j) { m[j] = -INFINITY; l[j] = 0.f; o[j] = 0.f; }

    int tmax = min(t0 + 15, G3);
    int smax, nchunk;
    if (t0 < NGT) { smax = NGT; nchunk = 1; }
    else {
        smax = (tmax >= G3) ? (G3 + 1) : ((tmax >= G2) ? G3 : G2);
        nchunk = 1 + (smax - G1 + 31) / 32;
    }
    const float scale = 0.03608439182435161f;   // 768^-0.5
    int krow = tid >> 3, kcol = (tid & 7) * 8;

    for (int ci = 0; ci < nchunk; ++ci) {
        int s0 = (ci == 0) ? 0 : G1 + (ci - 1) * 32;
        __syncthreads();
        {   // stage K,V chunk (32x64 each)
            const unsigned short* kp = qkv + (rowb + s0 + krow) * 2304 + 768 + h * 64 + kcol;
            uint4 ku = *(const uint4*)kp;
            uint4 vu = *(const uint4*)(kp + 768);
            Ks[krow][kcol + 0] = bfl(ku.x); Ks[krow][kcol + 1] = bfh(ku.x);
            Ks[krow][kcol + 2] = bfl(ku.y); Ks[krow][kcol + 3] = bfh(ku.y);
            Ks[krow][kcol + 4] = bfl(ku.z); Ks[krow][kcol + 5] = bfh(ku.z);
            Ks[krow][kcol + 6] = bfl(ku.w); Ks[krow][kcol + 7] = bfh(ku.w);
            Vs[krow][kcol + 0] = bfl(vu.x); Vs[krow][kcol + 1] = bfh(vu.x);
            Vs[krow][kcol + 2] = bfl(vu.y); Vs[krow][kcol + 3] = bfh(vu.y);
            Vs[krow][kcol + 4] = bfl(vu.z); Vs[krow][kcol + 5] = bfh(vu.z);
            Vs[krow][kcol + 6] = bfl(vu.w); Vs[krow][kcol + 7] = bfh(vu.w);
        }
        __syncthreads();
        int sl = lane & 31, dh = lane >> 5;
        #pragma unroll
        for (int j = 0; j < 4; ++j) {
            int t = t0 + wave * 4 + j;
            const float* qrow = Qs[wave * 4 + j];
            const float* kr = Ks[sl];
            float part = 0.f;
            #pragma unroll
            for (int i = 0; i < 32; i += 2) {
                float2 qv = *(const float2*)&qrow[dh * 32 + i];
                float2 kv = *(const float2*)&kr[dh * 32 + i];
                part += qv.x * kv.x + qv.y * kv.y;
            }
            part += __shfl_xor(part, 32);
            int s = s0 + sl;
            float score = (s < smax && keep2(t, s)) ? part * scale : -INFINITY;
            float cm = score;
            #pragma unroll
            for (int off = 1; off < 32; off <<= 1) cm = fmaxf(cm, __shfl_xor(cm, off));
            float mn = fmaxf(m[j], cm);
            float al = __expf(m[j] - mn);
            float p = __expf(score - mn);
            float ps = p;
            #pragma unroll
            for (int off = 1; off < 32; off <<= 1) ps += __shfl_xor(ps, off);
            l[j] = l[j] * al + ps;
            m[j] = mn;
            if (lane < 32) Ps[wave][lane] = p;
            float accv = o[j] * al;
            #pragma unroll 8
            for (int si = 0; si < 32; ++si)
                accv += Ps[wave][si] * Vs[si][lane];
            o[j] = accv;
        }
    }
    #pragma unroll
    for (int j = 0; j < 4; ++j) {
        int t = t0 + wave * 4 + j;
        if (t <= G3)
            ob[(rowb + t) * E + h * 64 + lane] = f2bf(o[j] / l[j]);
    }
}

// ============ middle tokens: o = v (bf16 copy, vectorized) ============
__global__ __launch_bounds__(256) void midcopy(
    const unsigned short* __restrict__ qkv, unsigned short* __restrict__ ob)
{
    int idx = blockIdx.x * 256 + threadIdx.x;   // Bsz*196*96
    if (idx >= Bsz * NGI * 96) return;
    int c8 = idx % 96;
    int r = idx / 96;
    int t = NGT + r % NGI;
    int b = r / NGI;
    const uint4* src = (const uint4*)(qkv + ((size_t)(b * T + t)) * 2304 + 1536 + c8 * 8);
    uint4* dst = (uint4*)(ob + ((size_t)(b * T + t)) * E + c8 * 8);
    *dst = *src;
}

// ================= output head (f32) =================
__global__ __launch_bounds__(256) void head_kernel(
    const float* __restrict__ x, const float* __restrict__ hw1,
    const float* __restrict__ hb1, const float* __restrict__ hw2,
    const float* __restrict__ hb2, float* __restrict__ out)
{
    int b = blockIdx.x;
    int tid = threadIdx.x;
    __shared__ float z[E];
    __shared__ float a1[E];
    const float* xr = x + ((size_t)(b * T + G3)) * E;
    for (int i = tid; i < E; i += 256) z[i] = xr[i];
    __syncthreads();
    for (int col = tid; col < E; col += 256) {
        float acc = hb1[col];
        for (int e = 0; e < E; ++e) acc += z[e] * hw1[(size_t)e * E + col];
        a1[col] = fmaxf(acc, 0.f);
    }
    __syncthreads();
    for (int col = tid; col < 64; col += 256) {
        float acc = hb2[col];
        for (int e = 0; e < E; ++e) acc += a1[e] * hw2[(size_t)e * 64 + col];
        out[b * 64 + col] = acc;
    }
}

// ================= launch =================
extern "C" void kernel_launch(void* const* d_in, const int* in_sizes, int n_in,
                              void* d_out, int out_size, void* d_ws, size_t ws_size,
                              hipStream_t stream) {
    const float* images     = (const float*)d_in[0];
    const int*   goals_txt  = (const int*)d_in[1];
    const float* goal_imgs  = (const float*)d_in[2];
    const float* patch_w    = (const float*)d_in[3];
    const float* patch_b    = (const float*)d_in[4];
    const float* text_emb   = (const float*)d_in[5];
    const float* action_emb = (const float*)d_in[6];
    const float* wq         = (const float*)d_in[7];
    const float* wk         = (const float*)d_in[8];
    const float* wv         = (const float*)d_in[9];
    const float* proj_w     = (const float*)d_in[10];
    const float* proj_b     = (const float*)d_in[11];
    const float* ln1_s      = (const float*)d_in[12];
    const float* ln1_b      = (const float*)d_in[13];
    const float* ln2_s      = (const float*)d_in[14];
    const float* ln2_b      = (const float*)d_in[15];
    const float* ff_w1      = (const float*)d_in[16];
    const float* ff_b1      = (const float*)d_in[17];
    const float* ff_w2      = (const float*)d_in[18];
    const float* ff_b2      = (const float*)d_in[19];
    const float* hw1        = (const float*)d_in[20];
    const float* hb1        = (const float*)d_in[21];
    const float* hw2        = (const float*)d_in[22];
    const float* hb2        = (const float*)d_in[23];
    float* out = (float*)d_out;

    char* w = (char*)d_ws;
    // ---- layout (bytes) ----
    float*          x      = (float*)w;                        // MP*768*4 = 30,670,848
    unsigned short* h      = (unsigned short*)(w + 30670848);  // MP*768*2 = 15,335,424
    unsigned short* ob     = (unsigned short*)(w + 46006272);  // MP*768*2 = 15,335,424
    float*          pos    = (float*)(w + 61341696);           // 621*768*4 = 1,907,712
    char*           big    = w + 63249408;                     // 61,341,696 shared region
    unsigned short* qkv    = (unsigned short*)big;             // MP*2304*2 = 46,006,272
    unsigned short* ffh    = (unsigned short*)big;             // MP*3072*2 = 61,341,696
    unsigned short* patches= (unsigned short*)big;             // MP2*768*2 = 14,548,992
    float*          pembed = (float*)(big + 14548992);         // MP2*768*4 = 29,097,984
    char*           wts    = big + 61341696;
    unsigned short* patchT = (unsigned short*)wts;                   // 768*768*2
    unsigned short* qkvT   = (unsigned short*)(wts + 1179648);       // 12*2304*768*2
    unsigned short* projT  = (unsigned short*)(wts + 1179648 + 42467328);
    unsigned short* ff1T   = (unsigned short*)(wts + 1179648 + 42467328 + 14155776);
    unsigned short* ff2T   = (unsigned short*)(wts + 1179648 + 42467328 + 14155776 + 56623104);
    // total = 295,640,064 bytes

    // POS + weight transposes
    pos_fill<<<(T * E + 255) / 256, 256, 0, stream>>>(pos);
    transpose_cast<<<dim3(24, 24, 1), dim3(32, 8), 0, stream>>>(
        patch_w, patchT, 768, 768, 0, 1, 0, 0);
    transpose_cast<<<dim3(2, 24, 144), dim3(32, 8), 0, stream>>>(
        wq, qkvT, 768, 64, 49152, 12, (long)2304 * 768, (long)64 * 768);
    transpose_cast<<<dim3(2, 24, 144), dim3(32, 8), 0, stream>>>(
        wk, qkvT + 768 * 768, 768, 64, 49152, 12, (long)2304 * 768, (long)64 * 768);
    transpose_cast<<<dim3(2, 24, 144), dim3(32, 8), 0, stream>>>(
        wv, qkvT + 2 * 768 * 768, 768, 64, 49152, 12, (long)2304 * 768, (long)64 * 768);
    transpose_cast<<<dim3(24, 24, 12), dim3(32, 8), 0, stream>>>(
        proj_w, projT, 768, 768, 589824, 1, 589824, 0);
    transpose_cast<<<dim3(96, 24, 12), dim3(32, 8), 0, stream>>>(
        ff_w1, ff1T, 768, 3072, 2359296, 1, 2359296, 0);
    transpose_cast<<<dim3(24, 96, 12), dim3(32, 8), 0, stream>>>(
        ff_w2, ff2T, 3072, 768, 2359296, 1, 2359296, 0);

    // embeddings
    embed_txt_act<<<(Bsz * 33 * E + 255) / 256, 256, 0, stream>>>(
        goals_txt, text_emb, action_emb, pos, x);
    const int NPE = Bsz * 588 * E;
    patch_ext<<<(NPE + 255) / 256, 256, 0, stream>>>(images, goal_imgs, patches);
    gemm_bf16<<<dim3(6, MP2 / 128), 256, 0, stream>>>(
        patches, patchT, pembed, nullptr, 768, 768, 0);
    patch_scatter<<<(NPE + 255) / 256, 256, 0, stream>>>(pembed, patch_b, pos, x);

    for (int l = 0; l < NL; ++l) {
        ln_kernel<<<TOK, 256, 0, stream>>>(x, h, ln1_s + l * E, ln1_b + l * E);
        gemm_bf16<<<dim3(18, MP / 128), 256, 0, stream>>>(
            h, qkvT + (size_t)l * 2304 * 768, qkv, nullptr, 2304, 768, 1);
        attn2<<<dim3(27, Bsz * NH), 256, 0, stream>>>(qkv, ob);
        midcopy<<<(Bsz * NGI * 96 + 255) / 256, 256, 0, stream>>>(qkv, ob);
        gemm_bf16<<<dim3(6, MP / 128), 256, 0, stream>>>(
            ob, projT + (size_t)l * 768 * 768, x, proj_b + l * E, 768, 768, 3);
        ln_kernel<<<TOK, 256, 0, stream>>>(x, h, ln2_s + l * E, ln2_b + l * E);
        gemm_bf16<<<dim3(24, MP / 128), 256, 0, stream>>>(
            h, ff1T + (size_t)l * FF * 768, ffh, ff_b1 + l * FF, FF, 768, 2);
        gemm_bf16<<<dim3(6, MP / 128), 256, 0, stream>>>(
            ffh, ff2T + (size_t)l * 768 * FF, x, ff_b2 + l * E, 768, FF, 3);
    }
    head_kernel<<<Bsz, 256, 0, stream>>>(x, hw1, hb1, hw2, hb2, out);
}

// Round 3
// 5305.870 us; speedup vs baseline: 6.9736x; 1.8945x over previous
//
#include <hip/hip_runtime.h>
#include <math.h>

// ---- problem constants ----
#define Bsz 16
#define KIMG 2
#define NPP 14
#define PSZ 16
#define E 768
#define NH 12
#define HS 64
#define NL 12
#define NGT 32
#define NGI 196
#define T 621           // NGT + NGI + NI + 1
#define TOK (Bsz * T)   // 9936
#define MP 9984         // TOK padded to 78*128
#define MP2 9472        // 9408 padded to 74*128
#define FF 3072
#define G1 228
#define G2 424
#define G3 620
#define LN_EPS 1e-5f

typedef __attribute__((ext_vector_type(8))) short bf16x8;
typedef __attribute__((ext_vector_type(4))) float f32x4;

__device__ __forceinline__ unsigned short f2bf(float f) {
    unsigned u = __float_as_uint(f);
    u += 0x7fffu + ((u >> 16) & 1u);   // RNE
    return (unsigned short)(u >> 16);
}
__device__ __forceinline__ float bfl(unsigned u) { return __uint_as_float(u << 16); }

__device__ __forceinline__ void gload16(const void* g, void* l) {
    __builtin_amdgcn_global_load_lds(
        (const __attribute__((address_space(1))) void*)g,
        (__attribute__((address_space(3))) void*)l, 16, 0, 0);
}

// ================= POS embedding (f64 math, matches numpy) =================
__global__ __launch_bounds__(256) void pos_fill(float* __restrict__ pos) {
    int idx = blockIdx.x * 256 + threadIdx.x;
    if (idx >= T * E) return;
    int e = idx % E;
    int t = idx / E;
    int jj = (e & 1) ? (e - 1) : e;
    double expo = (double)jj / (double)E;
    double ang = (double)t / pow(10000.0, expo);
    pos[idx] = (float)((e & 1) ? cos(ang) : sin(ang));
}

// ============ transpose+cast f32[R][C] -> bf16[C][R], batched ============
__global__ __launch_bounds__(256) void transpose_cast(
    const float* __restrict__ in, unsigned short* __restrict__ out,
    int R, int C, long inb, int per_g, long gs, long is)
{
    __shared__ float tl[32][33];
    int b = blockIdx.z;
    const float* ib = in + (size_t)b * inb;
    unsigned short* ob = out + (size_t)(b / per_g) * gs + (size_t)(b % per_g) * is;
    int tx = threadIdx.x, ty = threadIdx.y;
    int bx = blockIdx.x, by = blockIdx.y;
    #pragma unroll
    for (int i = 0; i < 4; ++i) {
        int r = by * 32 + ty + i * 8;
        int c = bx * 32 + tx;
        tl[ty + i * 8][tx] = ib[(size_t)r * C + c];
    }
    __syncthreads();
    #pragma unroll
    for (int i = 0; i < 4; ++i) {
        int orow = bx * 32 + ty + i * 8;
        int ocol = by * 32 + tx;
        ob[(size_t)orow * R + ocol] = f2bf(tl[tx][ty + i * 8]);
    }
}

// ============ text + action token embedding ============
__global__ __launch_bounds__(256) void embed_txt_act(
    const int* __restrict__ goals_txt, const float* __restrict__ text_emb,
    const float* __restrict__ action_emb, const float* __restrict__ pos,
    float* __restrict__ x)
{
    int idx = blockIdx.x * 256 + threadIdx.x;
    if (idx >= Bsz * 33 * E) return;
    int e = idx % E;
    int r = idx / E;
    int b = r / 33;
    int tt = r % 33;
    int t; float val;
    if (tt < NGT) {
        t = tt;
        int tok = goals_txt[b * NGT + tt];
        val = text_emb[(size_t)tok * E + e];
    } else {
        t = G3;
        val = action_emb[e];
    }
    x[((size_t)(b * T + t)) * E + e] = val + pos[(size_t)t * E + e];
}

// ============ patch extraction -> bf16 (B,588,768), gimg first ============
__global__ __launch_bounds__(256) void patch_ext(
    const float* __restrict__ images, const float* __restrict__ goal_imgs,
    unsigned short* __restrict__ patches)
{
    size_t idx = (size_t)blockIdx.x * 256 + threadIdx.x;
    if (idx >= (size_t)Bsz * 588 * E) return;
    int j = (int)(idx % E);
    int r = (int)(idx / E);
    int b = r / 588;
    int rr = r % 588;
    int pr = j / 48;
    int rem = j % 48;
    int pc = rem / 3;
    int c = rem % 3;
    float v;
    if (rr < NGI) {
        int pi = rr;
        int nr = pi / NPP, nc = pi % NPP;
        size_t src = ((size_t)b * 224 + (nr * PSZ + pr)) * 224 * 3
                   + (size_t)(nc * PSZ + pc) * 3 + c;
        v = goal_imgs[src];
    } else {
        int q = rr - NGI;
        int kk = q / NGI;
        int pi = q % NGI;
        int nr = pi / NPP, nc = pi % NPP;
        size_t src = (((size_t)(b * KIMG + kk)) * 224 + (nr * PSZ + pr)) * 224 * 3
                   + (size_t)(nc * PSZ + pc) * 3 + c;
        v = images[src];
    }
    patches[idx] = f2bf(v);
}

// ============ scatter patch embeddings into x with bias+pos ============
__global__ __launch_bounds__(256) void patch_scatter(
    const float* __restrict__ emb, const float* __restrict__ patch_b,
    const float* __restrict__ pos, float* __restrict__ x)
{
    size_t idx = (size_t)blockIdx.x * 256 + threadIdx.x;
    if (idx >= (size_t)Bsz * 588 * E) return;
    int e = (int)(idx % E);
    int r = (int)(idx / E);
    int b = r / 588;
    int rr = r % 588;
    int t = NGT + rr;
    x[((size_t)(b * T + t)) * E + e] = emb[idx] + patch_b[e] + pos[(size_t)t * E + e];
}

// ================= bf16 MFMA GEMM (global_load_lds staging) =================
// A bf16 [M][K] row-major, Bt bf16 [N][K] row-major, tile 128x128, BK=32.
// mode: 0 = f32 out, 1 = bf16 out, 2 = bf16 out relu(acc+bias), 3 = f32 out += acc+bias
__global__ __launch_bounds__(256) void gemm_bf16(
    const unsigned short* __restrict__ A, const unsigned short* __restrict__ Bt,
    void* __restrict__ C, const float* __restrict__ bias,
    int N, int Kd, int mode)
{
    __shared__ __align__(16) unsigned short As[128 * 32];
    __shared__ __align__(16) unsigned short Bs[128 * 32];
    int tid = threadIdx.x;
    int row0 = blockIdx.y * 128, col0 = blockIdx.x * 128;
    int wave = tid >> 6, lane = tid & 63;
    f32x4 acc[2][8];
    #pragma unroll
    for (int i = 0; i < 2; ++i)
        #pragma unroll
        for (int j = 0; j < 8; ++j) {
            f32x4 z = {0.f, 0.f, 0.f, 0.f};
            acc[i][j] = z;
        }
    // staging: per wave, two 16-row segments (1024 B = 64 lanes x 16 B) for A and B.
    // lane l covers shorts l*8 within the segment: row = l>>2, col = (l&3)*8 (pitch 32).
    int r16 = lane >> 2, c8 = (lane & 3) * 8;
    const unsigned short* gA0 = A + (size_t)(row0 + wave * 32 + r16) * Kd + c8;
    const unsigned short* gA1 = gA0 + (size_t)16 * Kd;
    const unsigned short* gB0 = Bt + (size_t)(col0 + wave * 32 + r16) * Kd + c8;
    const unsigned short* gB1 = gB0 + (size_t)16 * Kd;
    unsigned short* lA0 = As + (wave * 32) * 32;       // wave-uniform bases
    unsigned short* lA1 = As + (wave * 32 + 16) * 32;
    unsigned short* lB0 = Bs + (wave * 32) * 32;
    unsigned short* lB1 = Bs + (wave * 32 + 16) * 32;

    int mrow = wave * 32, quad = lane >> 4, l15 = lane & 15;
    for (int k0 = 0; k0 < Kd; k0 += 32) {
        __syncthreads();
        gload16(gA0 + k0, lA0);
        gload16(gA1 + k0, lA1);
        gload16(gB0 + k0, lB0);
        gload16(gB1 + k0, lB1);
        __syncthreads();
        bf16x8 af[2], bfr[8];
        af[0] = *(const bf16x8*)&As[(mrow + l15) * 32 + quad * 8];
        af[1] = *(const bf16x8*)&As[(mrow + 16 + l15) * 32 + quad * 8];
        #pragma unroll
        for (int nt = 0; nt < 8; ++nt)
            bfr[nt] = *(const bf16x8*)&Bs[(nt * 16 + l15) * 32 + quad * 8];
        #pragma unroll
        for (int mt = 0; mt < 2; ++mt)
            #pragma unroll
            for (int nt = 0; nt < 8; ++nt)
                acc[mt][nt] = __builtin_amdgcn_mfma_f32_16x16x32_bf16(
                    af[mt], bfr[nt], acc[mt][nt], 0, 0, 0);
    }
    #pragma unroll
    for (int mt = 0; mt < 2; ++mt) {
        #pragma unroll
        for (int nt = 0; nt < 8; ++nt) {
            int gcol = col0 + nt * 16 + l15;
            int grow0 = row0 + wave * 32 + mt * 16 + quad * 4;
            float bv = (mode >= 2 && bias) ? bias[gcol] : 0.f;
            #pragma unroll
            for (int r = 0; r < 4; ++r) {
                float v = acc[mt][nt][r] + bv;
                size_t off = (size_t)(grow0 + r) * N + gcol;
                if (mode == 0)      ((float*)C)[off] = v;
                else if (mode == 1) ((unsigned short*)C)[off] = f2bf(v);
                else if (mode == 2) ((unsigned short*)C)[off] = f2bf(fmaxf(v, 0.f));
                else                ((float*)C)[off] += v;
            }
        }
    }
}

// ================= LayerNorm: f32 in, bf16 out =================
__global__ __launch_bounds__(256) void ln_kernel(
    const float* __restrict__ x, unsigned short* __restrict__ h,
    const float* __restrict__ sg, const float* __restrict__ bg)
{
    int row = blockIdx.x;
    int tid = threadIdx.x;
    const float* xr = x + (size_t)row * E;
    float v0 = xr[tid], v1 = xr[tid + 256], v2 = xr[tid + 512];
    float sum = v0 + v1 + v2;
    float sq = v0 * v0 + v1 * v1 + v2 * v2;
    #pragma unroll
    for (int off = 1; off < 64; off <<= 1) {
        sum += __shfl_xor(sum, off);
        sq += __shfl_xor(sq, off);
    }
    __shared__ float rs[4], rq[4];
    if ((tid & 63) == 0) { rs[tid >> 6] = sum; rq[tid >> 6] = sq; }
    __syncthreads();
    float ts = rs[0] + rs[1] + rs[2] + rs[3];
    float tq = rq[0] + rq[1] + rq[2] + rq[3];
    float mean = ts * (1.0f / E);
    float var = tq * (1.0f / E) - mean * mean;
    float inv = 1.0f / sqrtf(var + LN_EPS);
    unsigned short* hr = h + (size_t)row * E;
    hr[tid]       = f2bf((v0 - mean) * inv * sg[tid]       + bg[tid]);
    hr[tid + 256] = f2bf((v1 - mean) * inv * sg[tid + 256] + bg[tid + 256]);
    hr[tid + 512] = f2bf((v2 - mean) * inv * sg[tid + 512] + bg[tid + 512]);
}

// ================= MFMA flash attention =================
__device__ __forceinline__ bool keep2(int t, int s) {
    if (s < NGT) return true;       // active t (t<32 or t>=228) always sees text
    if (s < G1) return false;
    if (s < G2) return true;        // visited only by t >= 228
    if (s < G3) return t >= G2;
    return t == G3;
}

// grid: (7 tile-groups, B*NH). 4 waves/block, one 16-t tile per wave.
// tiles: 0,1 -> t0 = {0,16}; 2..26 -> t0 = 228 + (i-2)*16 (covers 228..627, t>620 masked)
__global__ __launch_bounds__(256) void attn3(
    const unsigned short* __restrict__ qkv, unsigned short* __restrict__ ob)
{
    __shared__ __align__(16) unsigned short Ks[32 * 72];      // [s][k]  pitch 72
    __shared__ __align__(16) unsigned short Vt[64 * 40];      // [d][s]  pitch 40
    __shared__ __align__(16) unsigned short Ps[4][16 * 40];   // per-wave [t][s] pitch 40
    int bh = blockIdx.y;
    int h = bh % NH, b = bh / NH;
    int tid = threadIdx.x, wave = tid >> 6, lane = tid & 63;
    int quad = lane >> 4, l15 = lane & 15;
    int tileIdx = blockIdx.x * 4 + wave;
    bool wvalid = tileIdx < 27;
    int ti = wvalid ? tileIdx : 26;
    int t0 = (ti < 2) ? ti * 16 : G1 + (ti - 2) * 16;
    int tmax = min(t0 + 15, G3);
    int smax_w = (ti < 2) ? NGT : ((tmax >= G3) ? (G3 + 1) : ((tmax >= G2) ? G3 : G2));
    if (!wvalid) smax_w = 0;
    int lastTile = min(blockIdx.x * 4 + 3, 26);
    int lt0 = (lastTile < 2) ? lastTile * 16 : G1 + (lastTile - 2) * 16;
    int ltmax = min(lt0 + 15, G3);
    int blk_smax = (lastTile < 2) ? NGT
                 : ((ltmax >= G3) ? (G3 + 1) : ((ltmax >= G2) ? G3 : G2));
    int nchunk = (blk_smax <= NGT) ? 1 : 1 + (blk_smax - G1 + 31) / 32;
    size_t rowb = (size_t)b * T;

    // Q fragments (A-layout): lane holds Q[t0+l15][kc*32 + quad*8 + j]
    bf16x8 qf[2];
    {
        int tq = min(t0 + l15, G3);
        const unsigned short* qp = qkv + (rowb + tq) * 2304 + h * 64 + quad * 8;
        qf[0] = *(const bf16x8*)qp;
        qf[1] = *(const bf16x8*)(qp + 32);
    }
    float mrow[4] = {-INFINITY, -INFINITY, -INFINITY, -INFINITY};
    float lrow[4] = {0.f, 0.f, 0.f, 0.f};
    f32x4 oacc[4];
    #pragma unroll
    for (int nt = 0; nt < 4; ++nt) {
        f32x4 z = {0.f, 0.f, 0.f, 0.f};
        oacc[nt] = z;
    }
    int ks_s = tid >> 3, ks_c = (tid & 7) * 8;   // K staging: row/8-col-group
    int vs_s = tid & 31, vs_d = (tid >> 5) * 8;  // V staging (transposed write)
    const float scale = 0.03608439182435161f;    // 768^-0.5

    for (int ci = 0; ci < nchunk; ++ci) {
        int s0 = (ci == 0) ? 0 : G1 + (ci - 1) * 32;
        __syncthreads();
        {   // stage K [32][64] and V transposed [64][32]
            int sgk = min(s0 + ks_s, G3);
            const unsigned short* kp = qkv + (rowb + sgk) * 2304 + 768 + h * 64 + ks_c;
            *(uint4*)&Ks[ks_s * 72 + ks_c] = *(const uint4*)kp;
            int sgv = min(s0 + vs_s, G3);
            const unsigned short* vp = qkv + (rowb + sgv) * 2304 + 1536 + h * 64 + vs_d;
            uint4 vv = *(const uint4*)vp;
            unsigned short tmp[8];
            *(uint4*)tmp = vv;
            #pragma unroll
            for (int j = 0; j < 8; ++j) Vt[(vs_d + j) * 40 + vs_s] = tmp[j];
        }
        __syncthreads();
        if (s0 >= smax_w) continue;

        // QK^T: S[16t][32s] as two 16x16 C tiles
        f32x4 sv0 = {0.f, 0.f, 0.f, 0.f}, sv1 = {0.f, 0.f, 0.f, 0.f};
        {
            bf16x8 kf;
            kf = *(const bf16x8*)&Ks[l15 * 72 + quad * 8];
            sv0 = __builtin_amdgcn_mfma_f32_16x16x32_bf16(qf[0], kf, sv0, 0, 0, 0);
            kf = *(const bf16x8*)&Ks[l15 * 72 + 32 + quad * 8];
            sv0 = __builtin_amdgcn_mfma_f32_16x16x32_bf16(qf[1], kf, sv0, 0, 0, 0);
            kf = *(const bf16x8*)&Ks[(16 + l15) * 72 + quad * 8];
            sv1 = __builtin_amdgcn_mfma_f32_16x16x32_bf16(qf[0], kf, sv1, 0, 0, 0);
            kf = *(const bf16x8*)&Ks[(16 + l15) * 72 + 32 + quad * 8];
            sv1 = __builtin_amdgcn_mfma_f32_16x16x32_bf16(qf[1], kf, sv1, 0, 0, 0);
        }
        // online softmax; lane's C rows are t0 + quad*4 + r
        #pragma unroll
        for (int r = 0; r < 4; ++r) {
            int t = t0 + quad * 4 + r;
            int sA = s0 + l15, sB = s0 + 16 + l15;
            float a = (sA < smax_w && keep2(t, sA)) ? sv0[r] * scale : -INFINITY;
            float bb = (sB < smax_w && keep2(t, sB)) ? sv1[r] * scale : -INFINITY;
            float mx = fmaxf(a, bb);
            #pragma unroll
            for (int off = 1; off < 16; off <<= 1) mx = fmaxf(mx, __shfl_xor(mx, off));
            float mn = fmaxf(mrow[r], mx);
            float safe = (mn == -INFINITY) ? 0.f : mn;
            float alpha = __expf(mrow[r] - safe);
            float pa = __expf(a - safe), pb = __expf(bb - safe);
            float rs = pa + pb;
            #pragma unroll
            for (int off = 1; off < 16; off <<= 1) rs += __shfl_xor(rs, off);
            lrow[r] = lrow[r] * alpha + rs;
            mrow[r] = mn;
            Ps[wave][(quad * 4 + r) * 40 + l15] = f2bf(pa);
            Ps[wave][(quad * 4 + r) * 40 + 16 + l15] = f2bf(pb);
            oacc[0][r] *= alpha; oacc[1][r] *= alpha;
            oacc[2][r] *= alpha; oacc[3][r] *= alpha;
        }
        // PV: A = P[16t][32s] (LDS round trip), B = V[32s][16d] from Vt
        bf16x8 pf = *(const bf16x8*)&Ps[wave][l15 * 40 + quad * 8];
        #pragma unroll
        for (int nt = 0; nt < 4; ++nt) {
            bf16x8 vf = *(const bf16x8*)&Vt[(nt * 16 + l15) * 40 + quad * 8];
            oacc[nt] = __builtin_amdgcn_mfma_f32_16x16x32_bf16(pf, vf, oacc[nt], 0, 0, 0);
        }
    }
    if (wvalid) {
        #pragma unroll
        for (int r = 0; r < 4; ++r) {
            int t = t0 + quad * 4 + r;
            if (t > G3) continue;
            float inv = 1.f / lrow[r];
            #pragma unroll
            for (int nt = 0; nt < 4; ++nt)
                ob[(rowb + t) * E + h * 64 + nt * 16 + l15] = f2bf(oacc[nt][r] * inv);
        }
    }
}

// ============ middle tokens: o = v (bf16 copy, vectorized) ============
__global__ __launch_bounds__(256) void midcopy(
    const unsigned short* __restrict__ qkv, unsigned short* __restrict__ ob)
{
    int idx = blockIdx.x * 256 + threadIdx.x;   // Bsz*196*96
    if (idx >= Bsz * NGI * 96) return;
    int c8 = idx % 96;
    int r = idx / 96;
    int t = NGT + r % NGI;
    int b = r / NGI;
    const uint4* src = (const uint4*)(qkv + ((size_t)(b * T + t)) * 2304 + 1536 + c8 * 8);
    uint4* dst = (uint4*)(ob + ((size_t)(b * T + t)) * E + c8 * 8);
    *dst = *src;
}

// ================= output head (f32) =================
__global__ __launch_bounds__(256) void head_kernel(
    const float* __restrict__ x, const float* __restrict__ hw1,
    const float* __restrict__ hb1, const float* __restrict__ hw2,
    const float* __restrict__ hb2, float* __restrict__ out)
{
    int b = blockIdx.x;
    int tid = threadIdx.x;
    __shared__ float z[E];
    __shared__ float a1[E];
    const float* xr = x + ((size_t)(b * T + G3)) * E;
    for (int i = tid; i < E; i += 256) z[i] = xr[i];
    __syncthreads();
    for (int col = tid; col < E; col += 256) {
        float acc = hb1[col];
        for (int e = 0; e < E; ++e) acc += z[e] * hw1[(size_t)e * E + col];
        a1[col] = fmaxf(acc, 0.f);
    }
    __syncthreads();
    for (int col = tid; col < 64; col += 256) {
        float acc = hb2[col];
        for (int e = 0; e < E; ++e) acc += a1[e] * hw2[(size_t)e * 64 + col];
        out[b * 64 + col] = acc;
    }
}

// ================= launch =================
extern "C" void kernel_launch(void* const* d_in, const int* in_sizes, int n_in,
                              void* d_out, int out_size, void* d_ws, size_t ws_size,
                              hipStream_t stream) {
    const float* images     = (const float*)d_in[0];
    const int*   goals_txt  = (const int*)d_in[1];
    const float* goal_imgs  = (const float*)d_in[2];
    const float* patch_w    = (const float*)d_in[3];
    const float* patch_b    = (const float*)d_in[4];
    const float* text_emb   = (const float*)d_in[5];
    const float* action_emb = (const float*)d_in[6];
    const float* wq         = (const float*)d_in[7];
    const float* wk         = (const float*)d_in[8];
    const float* wv         = (const float*)d_in[9];
    const float* proj_w     = (const float*)d_in[10];
    const float* proj_b     = (const float*)d_in[11];
    const float* ln1_s      = (const float*)d_in[12];
    const float* ln1_b      = (const float*)d_in[13];
    const float* ln2_s      = (const float*)d_in[14];
    const float* ln2_b      = (const float*)d_in[15];
    const float* ff_w1      = (const float*)d_in[16];
    const float* ff_b1      = (const float*)d_in[17];
    const float* ff_w2      = (const float*)d_in[18];
    const float* ff_b2      = (const float*)d_in[19];
    const float* hw1        = (const float*)d_in[20];
    const float* hb1        = (const float*)d_in[21];
    const float* hw2        = (const float*)d_in[22];
    const float* hb2        = (const float*)d_in[23];
    float* out = (float*)d_out;

    char* w = (char*)d_ws;
    float*          x      = (float*)w;                        // MP*768*4
    unsigned short* h      = (unsigned short*)(w + 30670848);  // MP*768*2
    unsigned short* ob     = (unsigned short*)(w + 46006272);  // MP*768*2
    float*          pos    = (float*)(w + 61341696);           // 621*768*4
    char*           big    = w + 63249408;                     // shared region
    unsigned short* qkv    = (unsigned short*)big;             // MP*2304*2
    unsigned short* ffh    = (unsigned short*)big;             // MP*3072*2
    unsigned short* patches= (unsigned short*)big;             // MP2*768*2
    float*          pembed = (float*)(big + 14548992);         // MP2*768*4
    char*           wts    = big + 61341696;
    unsigned short* patchT = (unsigned short*)wts;
    unsigned short* qkvT   = (unsigned short*)(wts + 1179648);
    unsigned short* projT  = (unsigned short*)(wts + 1179648 + 42467328);
    unsigned short* ff1T   = (unsigned short*)(wts + 1179648 + 42467328 + 14155776);
    unsigned short* ff2T   = (unsigned short*)(wts + 1179648 + 42467328 + 14155776 + 56623104);

    pos_fill<<<(T * E + 255) / 256, 256, 0, stream>>>(pos);
    transpose_cast<<<dim3(24, 24, 1), dim3(32, 8), 0, stream>>>(
        patch_w, patchT, 768, 768, 0, 1, 0, 0);
    transpose_cast<<<dim3(2, 24, 144), dim3(32, 8), 0, stream>>>(
        wq, qkvT, 768, 64, 49152, 12, (long)2304 * 768, (long)64 * 768);
    transpose_cast<<<dim3(2, 24, 144), dim3(32, 8), 0, stream>>>(
        wk, qkvT + 768 * 768, 768, 64, 49152, 12, (long)2304 * 768, (long)64 * 768);
    transpose_cast<<<dim3(2, 24, 144), dim3(32, 8), 0, stream>>>(
        wv, qkvT + 2 * 768 * 768, 768, 64, 49152, 12, (long)2304 * 768, (long)64 * 768);
    transpose_cast<<<dim3(24, 24, 12), dim3(32, 8), 0, stream>>>(
        proj_w, projT, 768, 768, 589824, 1, 589824, 0);
    transpose_cast<<<dim3(96, 24, 12), dim3(32, 8), 0, stream>>>(
        ff_w1, ff1T, 768, 3072, 2359296, 1, 2359296, 0);
    transpose_cast<<<dim3(24, 96, 12), dim3(32, 8), 0, stream>>>(
        ff_w2, ff2T, 3072, 768, 2359296, 1, 2359296, 0);

    embed_txt_act<<<(Bsz * 33 * E + 255) / 256, 256, 0, stream>>>(
        goals_txt, text_emb, action_emb, pos, x);
    const int NPE = Bsz * 588 * E;
    patch_ext<<<(NPE + 255) / 256, 256, 0, stream>>>(images, goal_imgs, patches);
    gemm_bf16<<<dim3(6, MP2 / 128), 256, 0, stream>>>(
        patches, patchT, pembed, nullptr, 768, 768, 0);
    patch_scatter<<<(NPE + 255) / 256, 256, 0, stream>>>(pembed, patch_b, pos, x);

    for (int l = 0; l < NL; ++l) {
        ln_kernel<<<TOK, 256, 0, stream>>>(x, h, ln1_s + l * E, ln1_b + l * E);
        gemm_bf16<<<dim3(18, MP / 128), 256, 0, stream>>>(
            h, qkvT + (size_t)l * 2304 * 768, qkv, nullptr, 2304, 768, 1);
        attn3<<<dim3(7, Bsz * NH), 256, 0, stream>>>(qkv, ob);
        midcopy<<<(Bsz * NGI * 96 + 255) / 256, 256, 0, stream>>>(qkv, ob);
        gemm_bf16<<<dim3(6, MP / 128), 256, 0, stream>>>(
            ob, projT + (size_t)l * 768 * 768, x, proj_b + l * E, 768, 768, 3);
        ln_kernel<<<TOK, 256, 0, stream>>>(x, h, ln2_s + l * E, ln2_b + l * E);
        gemm_bf16<<<dim3(24, MP / 128), 256, 0, stream>>>(
            h, ff1T + (size_t)l * FF * 768, ffh, ff_b1 + l * FF, FF, 768, 2);
        gemm_bf16<<<dim3(6, MP / 128), 256, 0, stream>>>(
            ffh, ff2T + (size_t)l * 768 * FF, x, ff_b2 + l * E, 768, FF, 3);
    }
    head_kernel<<<Bsz, 256, 0, stream>>>(x, hw1, hb1, hw2, hb2, out);
}